// Round 2
// baseline (975.317 us; speedup 1.0000x reference)
//
#include <hip/hip_runtime.h>
#include <hip/hip_bf16.h>

#define NNODES 50000
#define NEDGES 800000

typedef short bf16x8 __attribute__((ext_vector_type(8)));
typedef float f32x4 __attribute__((ext_vector_type(4)));
typedef unsigned short u16;
typedef unsigned int u32;

__device__ __forceinline__ u16 f2bf(float f) {
    __hip_bfloat16 b = __float2bfloat16(f);   // RNE, hw cvt on gfx950
    return *reinterpret_cast<u16*>(&b);
}
__device__ __forceinline__ float silu(float x) {
    return x / (1.0f + __expf(-x));
}
__device__ __forceinline__ bf16x8 ld8(const u16* p) {
    return *(const bf16x8*)p;
}

// ---- transpose + fp32->bf16: src[K][N] f32 -> dst[N][K] bf16 ----
__global__ void transpose_cvt(const float* __restrict__ src, u16* __restrict__ dst,
                              int K, int N) {
    int i = blockIdx.x * 256 + threadIdx.x;
    if (i < K * N) {
        int n = i / K;          // K is 128 or 256 (power of two)
        int k = i - n * K;
        dst[i] = f2bf(src[k * N + n]);
    }
}

// ---- fp32 -> bf16 elementwise (h), 4 elems/thread ----
__global__ void cvt_bf16_4(const float* __restrict__ src, u16* __restrict__ dst, int n4) {
    int i = blockIdx.x * 256 + threadIdx.x;
    if (i < n4) {
        f32x4 v = *(const f32x4*)(src + i * 4);
        ushort4 o;
        o.x = f2bf(v[0]); o.y = f2bf(v[1]); o.z = f2bf(v[2]); o.w = f2bf(v[3]);
        *(ushort4*)(dst + i * 4) = o;
    }
}

struct __align__(16) EdgeShared {
    int   snd[16];
    int   rcv[16];
    float diff[16][4];
    float radial[16];
    float pc[16];
    u16   mbuf[16 * 136];   // 16 rows x 128 cols, stride 136 (16B multiple)
};

// Each wave handles 16 edges; block = 2 waves (32 edges).
__global__ __launch_bounds__(128) void edge_kernel(
    const u16* __restrict__ hbf, const float* __restrict__ pos,
    const int* __restrict__ snd, const int* __restrict__ rcv,
    const u16* __restrict__ eW1T, const float* __restrict__ eW1last,
    const float* __restrict__ eb1,
    const u16* __restrict__ eW2T, const float* __restrict__ eb2,
    const u16* __restrict__ pW1T, const float* __restrict__ pb1,
    const float* __restrict__ pW2,
    float* __restrict__ agg, float* __restrict__ posacc)
{
    __shared__ EdgeShared sh[2];
    const int wv   = threadIdx.x >> 6;
    const int lane = threadIdx.x & 63;
    const int m    = lane & 15;
    const int quad = lane >> 4;
    const int ksub = quad * 8;
    EdgeShared& S = sh[wv];
    const int e0 = (blockIdx.x * 2 + wv) * 16;

    if (lane < 16) {
        int e = e0 + lane;
        int s = snd[e], r = rcv[e];
        S.snd[lane] = s;
        S.rcv[lane] = r;
        float rad = 0.f;
        #pragma unroll
        for (int c = 0; c < 3; c++) {
            float d = pos[s * 3 + c] - pos[r * 3 + c];
            S.diff[lane][c] = d;
            rad += d * d;
        }
        S.radial[lane] = rad;
    }
    __syncthreads();

    // ---------- layer 1: silu([h_s,h_r,radial] @ eW1 + eb1) ----------
    f32x4 acc[8];
    #pragma unroll
    for (int c = 0; c < 8; c++) acc[c] = (f32x4){0.f, 0.f, 0.f, 0.f};
    const int sm = S.snd[m], rm = S.rcv[m];
    #pragma unroll
    for (int t = 0; t < 8; t++) {
        const u16* ap = (t < 4) ? (hbf + sm * 128 + t * 32 + ksub)
                                : (hbf + rm * 128 + (t - 4) * 32 + ksub);
        bf16x8 a = ld8(ap);
        #pragma unroll
        for (int c = 0; c < 8; c++) {
            bf16x8 b = ld8(eW1T + (c * 16 + m) * 256 + t * 32 + ksub);
            acc[c] = __builtin_amdgcn_mfma_f32_16x16x32_bf16(a, b, acc[c], 0, 0, 0);
        }
    }
    float rad4[4];
    #pragma unroll
    for (int r = 0; r < 4; r++) rad4[r] = S.radial[quad * 4 + r];
    #pragma unroll
    for (int c = 0; c < 8; c++) {
        int col = c * 16 + m;
        float wl = eW1last[col];
        float b1 = eb1[col];
        #pragma unroll
        for (int r = 0; r < 4; r++) {
            float v = acc[c][r] + rad4[r] * wl + b1;
            v = silu(v);
            S.mbuf[(quad * 4 + r) * 136 + col] = f2bf(v);
        }
    }
    __syncthreads();

    // ---------- layer 2: msg = silu(m1 @ eW2 + eb2) ----------
    f32x4 acc2[8];
    #pragma unroll
    for (int c = 0; c < 8; c++) acc2[c] = (f32x4){0.f, 0.f, 0.f, 0.f};
    #pragma unroll
    for (int t = 0; t < 4; t++) {
        bf16x8 a = *(const bf16x8*)&S.mbuf[m * 136 + t * 32 + ksub];
        #pragma unroll
        for (int c = 0; c < 8; c++) {
            bf16x8 b = ld8(eW2T + (c * 16 + m) * 128 + t * 32 + ksub);
            acc2[c] = __builtin_amdgcn_mfma_f32_16x16x32_bf16(a, b, acc2[c], 0, 0, 0);
        }
    }
    __syncthreads();  // mbuf reads done; safe to overwrite
    int rcv4[4];
    #pragma unroll
    for (int r = 0; r < 4; r++) rcv4[r] = S.rcv[quad * 4 + r];
    #pragma unroll
    for (int c = 0; c < 8; c++) {
        int col = c * 16 + m;
        float b2 = eb2[col];
        #pragma unroll
        for (int r = 0; r < 4; r++) {
            float v = silu(acc2[c][r] + b2);
            atomicAdd(&agg[rcv4[r] * 128 + col], v);
            S.mbuf[(quad * 4 + r) * 136 + col] = f2bf(v);
        }
    }
    __syncthreads();

    // ---------- pos head: pc = silu(msg @ pW1 + pb1) @ pW2 ----------
    f32x4 acc3[8];
    #pragma unroll
    for (int c = 0; c < 8; c++) acc3[c] = (f32x4){0.f, 0.f, 0.f, 0.f};
    #pragma unroll
    for (int t = 0; t < 4; t++) {
        bf16x8 a = *(const bf16x8*)&S.mbuf[m * 136 + t * 32 + ksub];
        #pragma unroll
        for (int c = 0; c < 8; c++) {
            bf16x8 b = ld8(pW1T + (c * 16 + m) * 128 + t * 32 + ksub);
            acc3[c] = __builtin_amdgcn_mfma_f32_16x16x32_bf16(a, b, acc3[c], 0, 0, 0);
        }
    }
    float p[4] = {0.f, 0.f, 0.f, 0.f};
    #pragma unroll
    for (int c = 0; c < 8; c++) {
        int col = c * 16 + m;
        float pb = pb1[col];
        float w2 = pW2[col];
        #pragma unroll
        for (int r = 0; r < 4; r++) {
            float tv = silu(acc3[c][r] + pb);
            p[r] += tv * w2;
        }
    }
    #pragma unroll
    for (int mask = 1; mask < 16; mask <<= 1) {
        #pragma unroll
        for (int r = 0; r < 4; r++) p[r] += __shfl_xor(p[r], mask);
    }
    if (m == 0) {
        #pragma unroll
        for (int r = 0; r < 4; r++) S.pc[quad * 4 + r] = p[r];
    }
    __syncthreads();
    if (lane < 48) {
        int el = lane / 3;
        int cc = lane - el * 3;
        float tr = S.diff[el][cc] * S.pc[el];
        tr = fminf(fmaxf(tr, -100.f), 100.f);
        atomicAdd(&posacc[S.snd[el] * 3 + cc], tr);
    }
}

// Node MLP: h_new = h + (silu([h,agg] @ nW1 + nb1) @ nW2 + nb2)
__global__ __launch_bounds__(128) void node_kernel(
    const u16* __restrict__ hbf, const float* __restrict__ h,
    const float* __restrict__ agg,
    const u16* __restrict__ nW1T, const float* __restrict__ nb1,
    const u16* __restrict__ nW2T, const float* __restrict__ nb2,
    float* __restrict__ out)
{
    __shared__ alignas(16) u16 mbuf[2][16 * 136];
    const int wv   = threadIdx.x >> 6;
    const int lane = threadIdx.x & 63;
    const int m    = lane & 15;
    const int quad = lane >> 4;
    const int ksub = quad * 8;
    const int n0 = (blockIdx.x * 2 + wv) * 16;
    int node_m = n0 + m;
    if (node_m >= NNODES) node_m = NNODES - 1;

    f32x4 acc[8];
    #pragma unroll
    for (int c = 0; c < 8; c++) acc[c] = (f32x4){0.f, 0.f, 0.f, 0.f};
    #pragma unroll
    for (int t = 0; t < 8; t++) {
        bf16x8 a;
        if (t < 4) {
            a = ld8(hbf + node_m * 128 + t * 32 + ksub);
        } else {
            const float* ap = agg + node_m * 128 + (t - 4) * 32 + ksub;
            f32x4 lo = *(const f32x4*)ap;
            f32x4 hi = *(const f32x4*)(ap + 4);
            #pragma unroll
            for (int j = 0; j < 4; j++) {
                a[j]     = (short)f2bf(lo[j]);
                a[4 + j] = (short)f2bf(hi[j]);
            }
        }
        #pragma unroll
        for (int c = 0; c < 8; c++) {
            bf16x8 b = ld8(nW1T + (c * 16 + m) * 256 + t * 32 + ksub);
            acc[c] = __builtin_amdgcn_mfma_f32_16x16x32_bf16(a, b, acc[c], 0, 0, 0);
        }
    }
    #pragma unroll
    for (int c = 0; c < 8; c++) {
        int col = c * 16 + m;
        float b1 = nb1[col];
        #pragma unroll
        for (int r = 0; r < 4; r++) {
            float v = silu(acc[c][r] + b1);
            mbuf[wv][(quad * 4 + r) * 136 + col] = f2bf(v);
        }
    }
    __syncthreads();

    f32x4 acc2[8];
    #pragma unroll
    for (int c = 0; c < 8; c++) acc2[c] = (f32x4){0.f, 0.f, 0.f, 0.f};
    #pragma unroll
    for (int t = 0; t < 4; t++) {
        bf16x8 a = *(const bf16x8*)&mbuf[wv][m * 136 + t * 32 + ksub];
        #pragma unroll
        for (int c = 0; c < 8; c++) {
            bf16x8 b = ld8(nW2T + (c * 16 + m) * 128 + t * 32 + ksub);
            acc2[c] = __builtin_amdgcn_mfma_f32_16x16x32_bf16(a, b, acc2[c], 0, 0, 0);
        }
    }
    #pragma unroll
    for (int c = 0; c < 8; c++) {
        int col = c * 16 + m;
        float b2 = nb2[col];
        #pragma unroll
        for (int r = 0; r < 4; r++) {
            int node_r = n0 + quad * 4 + r;
            if (node_r < NNODES) {
                float v = acc2[c][r] + b2 + h[node_r * 128 + col];
                out[node_r * 128 + col] = v;
            }
        }
    }
}

__global__ void pos_kernel(const float* __restrict__ pos,
                           const float* __restrict__ posacc,
                           float* __restrict__ out) {
    int i = blockIdx.x * 256 + threadIdx.x;
    if (i < NNODES * 3) {
        out[NNODES * 128 + i] = pos[i] + posacc[i];
    }
}

extern "C" void kernel_launch(void* const* d_in, const int* in_sizes, int n_in,
                              void* d_out, int out_size, void* d_ws, size_t ws_size,
                              hipStream_t stream) {
    (void)in_sizes; (void)n_in; (void)out_size; (void)ws_size;
    const float* h   = (const float*)d_in[0];
    const float* pos = (const float*)d_in[1];
    const int*   snd = (const int*)d_in[2];
    const int*   rcv = (const int*)d_in[3];
    const float* eW1 = (const float*)d_in[4];
    const float* eb1 = (const float*)d_in[5];
    const float* eW2 = (const float*)d_in[6];
    const float* eb2 = (const float*)d_in[7];
    const float* nW1 = (const float*)d_in[8];
    const float* nb1 = (const float*)d_in[9];
    const float* nW2 = (const float*)d_in[10];
    const float* nb2 = (const float*)d_in[11];
    const float* pW1 = (const float*)d_in[12];
    const float* pb1 = (const float*)d_in[13];
    const float* pW2 = (const float*)d_in[14];
    float* out = (float*)d_out;

    float* agg    = (float*)d_ws;                       // [N,128] f32
    float* posacc = agg + (size_t)NNODES * 128;         // [N,3] f32
    u16* hbf  = (u16*)(posacc + (size_t)NNODES * 3);    // [N,128] bf16
    u16* eW1T = hbf + (size_t)NNODES * 128;             // [128][256]
    u16* eW2T = eW1T + 128 * 256;                       // [128][128]
    u16* pW1T = eW2T + 128 * 128;                       // [128][128]
    u16* nW1T = pW1T + 128 * 128;                       // [128][256]
    u16* nW2T = nW1T + 128 * 256;                       // [128][128]

    // zero agg + posacc (contiguous)
    hipMemsetAsync(agg, 0, (size_t)NNODES * 131 * sizeof(float), stream);

    cvt_bf16_4<<<(NNODES * 128 / 4 + 255) / 256, 256, 0, stream>>>(h, hbf, NNODES * 128 / 4);
    transpose_cvt<<<(256 * 128 + 255) / 256, 256, 0, stream>>>(eW1, eW1T, 256, 128);
    transpose_cvt<<<(128 * 128 + 255) / 256, 256, 0, stream>>>(eW2, eW2T, 128, 128);
    transpose_cvt<<<(128 * 128 + 255) / 256, 256, 0, stream>>>(pW1, pW1T, 128, 128);
    transpose_cvt<<<(256 * 128 + 255) / 256, 256, 0, stream>>>(nW1, nW1T, 256, 128);
    transpose_cvt<<<(128 * 128 + 255) / 256, 256, 0, stream>>>(nW2, nW2T, 128, 128);

    edge_kernel<<<NEDGES / 32, 128, 0, stream>>>(
        hbf, pos, snd, rcv,
        eW1T, eW1 + 256 * 128, eb1,
        eW2T, eb2, pW1T, pb1, pW2,
        agg, posacc);

    node_kernel<<<(NNODES + 31) / 32, 128, 0, stream>>>(
        hbf, h, agg, nW1T, nb1, nW2T, nb2, out);

    pos_kernel<<<(NNODES * 3 + 255) / 256, 256, 0, stream>>>(pos, posacc, out);
}

// Round 3
// 643.958 us; speedup vs baseline: 1.5146x; 1.5146x over previous
//
#include <hip/hip_runtime.h>
#include <hip/hip_bf16.h>

#define NNODES 50000
#define NEDGES 800000
#define EB 512   // edge-kernel grid (2 blocks/CU)
#define NB 512   // node-kernel grid

typedef short bf16x8 __attribute__((ext_vector_type(8)));
typedef float f32x4 __attribute__((ext_vector_type(4)));
typedef unsigned short u16;
typedef unsigned int u32;

__device__ __forceinline__ u16 f2bf(float f) {
    __hip_bfloat16 b = __float2bfloat16(f);   // RNE, hw cvt
    return *reinterpret_cast<u16*>(&b);
}
__device__ __forceinline__ float silu(float x) {
    return x / (1.0f + __expf(-x));
}
__device__ __forceinline__ bf16x8 ld8(const u16* p) {
    return *(const bf16x8*)p;
}
__device__ __forceinline__ f32x4 mfma16(bf16x8 a, bf16x8 b, f32x4 c) {
    return __builtin_amdgcn_mfma_f32_16x16x32_bf16(a, b, c, 0, 0, 0);
}

// ---- transpose + fp32->bf16: src[K][N] f32 -> dst[N][K] bf16 ----
__global__ void transpose_cvt(const float* __restrict__ src, u16* __restrict__ dst,
                              int K, int N) {
    int i = blockIdx.x * 256 + threadIdx.x;
    if (i < K * N) {
        int n = i / K;
        int k = i - n * K;
        dst[i] = f2bf(src[k * N + n]);
    }
}

// ---- fp32 -> bf16 elementwise (h), 4 elems/thread ----
__global__ void cvt_bf16_4(const float* __restrict__ src, u16* __restrict__ dst, int n4) {
    int i = blockIdx.x * 256 + threadIdx.x;
    if (i < n4) {
        f32x4 v = *(const f32x4*)(src + i * 4);
        ushort4 o;
        o.x = f2bf(v[0]); o.y = f2bf(v[1]); o.z = f2bf(v[2]); o.w = f2bf(v[3]);
        *(ushort4*)(dst + i * 4) = o;
    }
}

struct __align__(16) EdgeLds {
    u16   astage[64 * 264];   // 64 rows x 528B (512B data + 16B pad -> conflict-free b128 reads)
    u16   m1[64 * 136];       // 64 x 128, stride 136 (272B, 16B-mult)
    u16   msg[64 * 136];
    int   snd[64];
    int   rcv[64];
    float radial[64];
    float diff[64][4];
    float pcpart[4][64];
};

// Block = 4 waves (256 thr). N-split: wave w owns output cols [32w,32w+32).
// Weights live in registers for the whole kernel (32 B-frags = 128 VGPRs).
// Grid-stride over 64-edge tiles.
__global__ __launch_bounds__(256, 2) void edge_kernel(
    const u16* __restrict__ hbf, const float* __restrict__ pos,
    const int* __restrict__ snd, const int* __restrict__ rcv,
    const u16* __restrict__ eW1T, const float* __restrict__ eW1last,
    const float* __restrict__ eb1,
    const u16* __restrict__ eW2T, const float* __restrict__ eb2,
    const u16* __restrict__ pW1T, const float* __restrict__ pb1,
    const float* __restrict__ pW2,
    float* __restrict__ agg, float* __restrict__ posacc)
{
    __shared__ EdgeLds S;
    const int tid  = threadIdx.x;
    const int w    = tid >> 6;
    const int lane = tid & 63;
    const int m    = lane & 15;
    const int quad = lane >> 4;
    const int ksub = quad * 8;

    // ---- persistent weight fragments (once per kernel) ----
    bf16x8 bw1[8][2], bw2[4][2], bp1[4][2];
    float wlastv[2], b1v[2], b2v[2], pb1v[2], pw2v[2];
    #pragma unroll
    for (int cc = 0; cc < 2; cc++) {
        int col = (2 * w + cc) * 16 + m;
        #pragma unroll
        for (int t = 0; t < 8; t++)
            bw1[t][cc] = ld8(eW1T + col * 256 + t * 32 + ksub);
        #pragma unroll
        for (int t = 0; t < 4; t++) {
            bw2[t][cc] = ld8(eW2T + col * 128 + t * 32 + ksub);
            bp1[t][cc] = ld8(pW1T + col * 128 + t * 32 + ksub);
        }
        wlastv[cc] = eW1last[col];
        b1v[cc]    = eb1[col];
        b2v[cc]    = eb2[col];
        pb1v[cc]   = pb1[col];
        pw2v[cc]   = pW2[col];
    }

    for (int base = blockIdx.x * 64; base < NEDGES; base += gridDim.x * 64) {
        __syncthreads();   // protect LDS from previous iteration's readers
        // ---- edge meta ----
        if (tid < 64) {
            int e = base + tid;
            int s = snd[e], r = rcv[e];
            S.snd[tid] = s; S.rcv[tid] = r;
            float rad = 0.f;
            #pragma unroll
            for (int c = 0; c < 3; c++) {
                float d = pos[s * 3 + c] - pos[r * 3 + c];
                S.diff[tid][c] = d;
                rad += d * d;
            }
            S.radial[tid] = rad;
        }
        __syncthreads();
        // ---- stage A rows [h_s | h_r] for 64 edges (8 x 16B chunks/thread) ----
        #pragma unroll
        for (int k = 0; k < 8; k++) {
            int cid = tid + k * 256;          // 0..2047
            int e  = cid >> 5;
            int hh = (cid >> 4) & 1;
            int p  = cid & 15;
            int node = hh ? S.rcv[e] : S.snd[e];
            bf16x8 v = ld8(hbf + node * 128 + p * 8);
            *(bf16x8*)&S.astage[e * 264 + hh * 128 + p * 8] = v;
        }
        __syncthreads();
        // ---- layer 1: m1 = silu([h_s,h_r] @ eW1 + radial*w_last + b1) ----
        #pragma unroll
        for (int mt = 0; mt < 4; mt++) {
            f32x4 acc0 = (f32x4){0,0,0,0}, acc1 = (f32x4){0,0,0,0};
            #pragma unroll
            for (int t = 0; t < 8; t++) {
                bf16x8 a = *(const bf16x8*)&S.astage[(mt * 16 + m) * 264 + t * 32 + ksub];
                acc0 = mfma16(a, bw1[t][0], acc0);
                acc1 = mfma16(a, bw1[t][1], acc1);
            }
            #pragma unroll
            for (int cc = 0; cc < 2; cc++) {
                f32x4 acc = cc ? acc1 : acc0;
                int col = (2 * w + cc) * 16 + m;
                #pragma unroll
                for (int r = 0; r < 4; r++) {
                    int row = mt * 16 + quad * 4 + r;
                    float v = acc[r] + S.radial[row] * wlastv[cc] + b1v[cc];
                    S.m1[row * 136 + col] = f2bf(silu(v));
                }
            }
        }
        __syncthreads();
        // ---- layer 2: msg = silu(m1 @ eW2 + b2); agg atomics ----
        #pragma unroll
        for (int mt = 0; mt < 4; mt++) {
            f32x4 acc0 = (f32x4){0,0,0,0}, acc1 = (f32x4){0,0,0,0};
            #pragma unroll
            for (int t = 0; t < 4; t++) {
                bf16x8 a = *(const bf16x8*)&S.m1[(mt * 16 + m) * 136 + t * 32 + ksub];
                acc0 = mfma16(a, bw2[t][0], acc0);
                acc1 = mfma16(a, bw2[t][1], acc1);
            }
            #pragma unroll
            for (int cc = 0; cc < 2; cc++) {
                f32x4 acc = cc ? acc1 : acc0;
                int col = (2 * w + cc) * 16 + m;
                #pragma unroll
                for (int r = 0; r < 4; r++) {
                    int row = mt * 16 + quad * 4 + r;
                    float v = silu(acc[r] + b2v[cc]);
                    S.msg[row * 136 + col] = f2bf(v);
                    atomicAdd(&agg[S.rcv[row] * 128 + col], v);
                }
            }
        }
        __syncthreads();
        // ---- pos head: pc = silu(msg @ pW1 + pb1) @ pW2 (partial per wave) ----
        #pragma unroll
        for (int mt = 0; mt < 4; mt++) {
            f32x4 acc0 = (f32x4){0,0,0,0}, acc1 = (f32x4){0,0,0,0};
            #pragma unroll
            for (int t = 0; t < 4; t++) {
                bf16x8 a = *(const bf16x8*)&S.msg[(mt * 16 + m) * 136 + t * 32 + ksub];
                acc0 = mfma16(a, bp1[t][0], acc0);
                acc1 = mfma16(a, bp1[t][1], acc1);
            }
            float p4[4];
            #pragma unroll
            for (int r = 0; r < 4; r++)
                p4[r] = silu(acc0[r] + pb1v[0]) * pw2v[0]
                      + silu(acc1[r] + pb1v[1]) * pw2v[1];
            #pragma unroll
            for (int mask = 1; mask < 16; mask <<= 1) {
                #pragma unroll
                for (int r = 0; r < 4; r++) p4[r] += __shfl_xor(p4[r], mask);
            }
            if (m == 0) {
                #pragma unroll
                for (int r = 0; r < 4; r++)
                    S.pcpart[w][mt * 16 + quad * 4 + r] = p4[r];
            }
        }
        __syncthreads();
        // ---- combine pc, trans clip, posacc atomics ----
        if (tid < 192) {
            int e = tid / 3, c = tid - e * 3;
            float pc = S.pcpart[0][e] + S.pcpart[1][e] + S.pcpart[2][e] + S.pcpart[3][e];
            float tr = S.diff[e][c] * pc;
            tr = fminf(fmaxf(tr, -100.f), 100.f);
            atomicAdd(&posacc[S.snd[e] * 3 + c], tr);
        }
    }
}

// Node MLP, same N-split structure: h_new = h + (silu([h,agg]@nW1+nb1)@nW2+nb2)
__global__ __launch_bounds__(256, 2) void node_kernel(
    const u16* __restrict__ hbf, const float* __restrict__ h,
    const float* __restrict__ agg,
    const u16* __restrict__ nW1T, const float* __restrict__ nb1,
    const u16* __restrict__ nW2T, const float* __restrict__ nb2,
    float* __restrict__ out)
{
    __shared__ u16 m1[64 * 136];
    const int tid  = threadIdx.x;
    const int w    = tid >> 6;
    const int lane = tid & 63;
    const int m    = lane & 15;
    const int quad = lane >> 4;
    const int ksub = quad * 8;

    bf16x8 bw1[8][2], bw2[4][2];
    float b1v[2], b2v[2];
    #pragma unroll
    for (int cc = 0; cc < 2; cc++) {
        int col = (2 * w + cc) * 16 + m;
        #pragma unroll
        for (int t = 0; t < 8; t++)
            bw1[t][cc] = ld8(nW1T + col * 256 + t * 32 + ksub);
        #pragma unroll
        for (int t = 0; t < 4; t++)
            bw2[t][cc] = ld8(nW2T + col * 128 + t * 32 + ksub);
        b1v[cc] = nb1[col];
        b2v[cc] = nb2[col];
    }

    const int ntiles = (NNODES + 63) / 64;   // 782
    for (int it = blockIdx.x; it < ntiles; it += gridDim.x) {
        int base = it * 64;
        __syncthreads();
        #pragma unroll
        for (int mt = 0; mt < 4; mt++) {
            int node_m = base + mt * 16 + m;
            if (node_m >= NNODES) node_m = NNODES - 1;
            f32x4 acc0 = (f32x4){0,0,0,0}, acc1 = (f32x4){0,0,0,0};
            #pragma unroll
            for (int t = 0; t < 8; t++) {
                bf16x8 a;
                if (t < 4) {
                    a = ld8(hbf + node_m * 128 + t * 32 + ksub);
                } else {
                    const float* ap = agg + node_m * 128 + (t - 4) * 32 + ksub;
                    f32x4 lo = *(const f32x4*)ap;
                    f32x4 hi = *(const f32x4*)(ap + 4);
                    #pragma unroll
                    for (int j = 0; j < 4; j++) {
                        a[j]     = (short)f2bf(lo[j]);
                        a[4 + j] = (short)f2bf(hi[j]);
                    }
                }
                acc0 = mfma16(a, bw1[t][0], acc0);
                acc1 = mfma16(a, bw1[t][1], acc1);
            }
            #pragma unroll
            for (int cc = 0; cc < 2; cc++) {
                f32x4 acc = cc ? acc1 : acc0;
                int col = (2 * w + cc) * 16 + m;
                #pragma unroll
                for (int r = 0; r < 4; r++) {
                    int row = mt * 16 + quad * 4 + r;
                    m1[row * 136 + col] = f2bf(silu(acc[r] + b1v[cc]));
                }
            }
        }
        __syncthreads();
        #pragma unroll
        for (int mt = 0; mt < 4; mt++) {
            f32x4 acc0 = (f32x4){0,0,0,0}, acc1 = (f32x4){0,0,0,0};
            #pragma unroll
            for (int t = 0; t < 4; t++) {
                bf16x8 a = *(const bf16x8*)&m1[(mt * 16 + m) * 136 + t * 32 + ksub];
                acc0 = mfma16(a, bw2[t][0], acc0);
                acc1 = mfma16(a, bw2[t][1], acc1);
            }
            #pragma unroll
            for (int cc = 0; cc < 2; cc++) {
                f32x4 acc = cc ? acc1 : acc0;
                int col = (2 * w + cc) * 16 + m;
                #pragma unroll
                for (int r = 0; r < 4; r++) {
                    int node_r = base + mt * 16 + quad * 4 + r;
                    if (node_r < NNODES)
                        out[node_r * 128 + col] = acc[r] + b2v[cc] + h[node_r * 128 + col];
                }
            }
        }
    }
}

__global__ void pos_kernel(const float* __restrict__ pos,
                           const float* __restrict__ posacc,
                           float* __restrict__ out) {
    int i = blockIdx.x * 256 + threadIdx.x;
    if (i < NNODES * 3) {
        out[NNODES * 128 + i] = pos[i] + posacc[i];
    }
}

extern "C" void kernel_launch(void* const* d_in, const int* in_sizes, int n_in,
                              void* d_out, int out_size, void* d_ws, size_t ws_size,
                              hipStream_t stream) {
    (void)in_sizes; (void)n_in; (void)out_size; (void)ws_size;
    const float* h   = (const float*)d_in[0];
    const float* pos = (const float*)d_in[1];
    const int*   snd = (const int*)d_in[2];
    const int*   rcv = (const int*)d_in[3];
    const float* eW1 = (const float*)d_in[4];
    const float* eb1 = (const float*)d_in[5];
    const float* eW2 = (const float*)d_in[6];
    const float* eb2 = (const float*)d_in[7];
    const float* nW1 = (const float*)d_in[8];
    const float* nb1 = (const float*)d_in[9];
    const float* nW2 = (const float*)d_in[10];
    const float* nb2 = (const float*)d_in[11];
    const float* pW1 = (const float*)d_in[12];
    const float* pb1 = (const float*)d_in[13];
    const float* pW2 = (const float*)d_in[14];
    float* out = (float*)d_out;

    float* agg    = (float*)d_ws;                       // [N,128] f32
    float* posacc = agg + (size_t)NNODES * 128;         // [N,3] f32
    u16* hbf  = (u16*)(posacc + (size_t)NNODES * 3);    // [N,128] bf16
    u16* eW1T = hbf + (size_t)NNODES * 128;             // [128][256]
    u16* eW2T = eW1T + 128 * 256;                       // [128][128]
    u16* pW1T = eW2T + 128 * 128;                       // [128][128]
    u16* nW1T = pW1T + 128 * 128;                       // [128][256]
    u16* nW2T = nW1T + 128 * 256;                       // [128][128]

    hipMemsetAsync(agg, 0, (size_t)NNODES * 131 * sizeof(float), stream);

    cvt_bf16_4<<<(NNODES * 128 / 4 + 255) / 256, 256, 0, stream>>>(h, hbf, NNODES * 128 / 4);
    transpose_cvt<<<(256 * 128 + 255) / 256, 256, 0, stream>>>(eW1, eW1T, 256, 128);
    transpose_cvt<<<(128 * 128 + 255) / 256, 256, 0, stream>>>(eW2, eW2T, 128, 128);
    transpose_cvt<<<(128 * 128 + 255) / 256, 256, 0, stream>>>(pW1, pW1T, 128, 128);
    transpose_cvt<<<(256 * 128 + 255) / 256, 256, 0, stream>>>(nW1, nW1T, 256, 128);
    transpose_cvt<<<(128 * 128 + 255) / 256, 256, 0, stream>>>(nW2, nW2T, 128, 128);

    edge_kernel<<<EB, 256, 0, stream>>>(
        hbf, pos, snd, rcv,
        eW1T, eW1 + 256 * 128, eb1,
        eW2T, eb2, pW1T, pb1, pW2,
        agg, posacc);

    node_kernel<<<NB, 256, 0, stream>>>(
        hbf, h, agg, nW1T, nb1, nW2T, nb2, out);

    pos_kernel<<<(NNODES * 3 + 255) / 256, 256, 0, stream>>>(pos, posacc, out);
}

// Round 4
// 515.988 us; speedup vs baseline: 1.8902x; 1.2480x over previous
//
#include <hip/hip_runtime.h>
#include <hip/hip_bf16.h>

#define NNODES 50000
#define NEDGES 800000
#define EB 1024          // edge grid: 4 blocks/CU resident
#define SCAN_BLOCKS 196  // ceil(50000/256)

typedef short bf16x8 __attribute__((ext_vector_type(8)));
typedef float f32x4 __attribute__((ext_vector_type(4)));
typedef unsigned short u16;
typedef unsigned int u32;

union U4 { ushort4 v; u16 a[4]; };

__device__ __forceinline__ u16 f2bf(float f) {
    __hip_bfloat16 b = __float2bfloat16(f);
    return *reinterpret_cast<u16*>(&b);
}
__device__ __forceinline__ float bf2f(u16 v) {
    u32 u = ((u32)v) << 16;
    return __uint_as_float(u);
}
__device__ __forceinline__ float silu(float x) {
    return x / (1.0f + __expf(-x));
}
__device__ __forceinline__ bf16x8 ld8(const u16* p) {
    return *(const bf16x8*)p;
}
__device__ __forceinline__ f32x4 mfma16(bf16x8 a, bf16x8 b, f32x4 c) {
    return __builtin_amdgcn_mfma_f32_16x16x32_bf16(a, b, c, 0, 0, 0);
}

// ---- transpose + fp32->bf16: src[K][N] f32 -> dst[N][K] bf16 ----
__global__ void transpose_cvt(const float* __restrict__ src, u16* __restrict__ dst,
                              int K, int N) {
    int i = blockIdx.x * 256 + threadIdx.x;
    if (i < K * N) {
        int n = i / K;
        int k = i - n * K;
        dst[i] = f2bf(src[k * N + n]);
    }
}

// ---- P precompute: P[n][0:128]=h@eW1a, [128:256]=h@eW1b, [256:384]=h@nW1a ----
__global__ __launch_bounds__(256) void gemm_p(
    const float* __restrict__ h, const u16* __restrict__ eW1T,
    const u16* __restrict__ nW1T, u16* __restrict__ P)
{
    const int tid  = threadIdx.x;
    const int w    = tid >> 6;
    const int lane = tid & 63;
    const int m    = lane & 15;
    const int quad = lane >> 4;
    const int ksub = quad * 8;

    bf16x8 bw[4][6];
    #pragma unroll
    for (int cc = 0; cc < 6; cc++) {
        int C = 96 * w + 16 * cc + m;
        const u16* bp;
        if (C < 128)      bp = eW1T + C * 256;
        else if (C < 256) bp = eW1T + (C - 128) * 256 + 128;
        else              bp = nW1T + (C - 256) * 256;
        #pragma unroll
        for (int t = 0; t < 4; t++) bw[t][cc] = ld8(bp + t * 32 + ksub);
    }
    const int base = blockIdx.x * 64;
    #pragma unroll
    for (int mt = 0; mt < 4; mt++) {
        int nm = base + mt * 16 + m;
        if (nm >= NNODES) nm = NNODES - 1;
        bf16x8 afr[4];
        #pragma unroll
        for (int t = 0; t < 4; t++) {
            const float* ap = h + (size_t)nm * 128 + t * 32 + ksub;
            f32x4 lo = *(const f32x4*)ap;
            f32x4 hi = *(const f32x4*)(ap + 4);
            #pragma unroll
            for (int j = 0; j < 4; j++) {
                afr[t][j]     = (short)f2bf(lo[j]);
                afr[t][4 + j] = (short)f2bf(hi[j]);
            }
        }
        f32x4 acc[6];
        #pragma unroll
        for (int cc = 0; cc < 6; cc++) acc[cc] = (f32x4){0,0,0,0};
        #pragma unroll
        for (int t = 0; t < 4; t++)
            #pragma unroll
            for (int cc = 0; cc < 6; cc++)
                acc[cc] = mfma16(afr[t], bw[t][cc], acc[cc]);
        #pragma unroll
        for (int cc = 0; cc < 6; cc++) {
            int C = 96 * w + 16 * cc + m;
            #pragma unroll
            for (int r = 0; r < 4; r++) {
                int nr = base + mt * 16 + quad * 4 + r;
                if (nr < NNODES) P[(size_t)nr * 384 + C] = f2bf(acc[cc][r]);
            }
        }
    }
}

// ---- receiver sort: histogram + scan + scatter ----
__global__ void hist_kernel(const int* __restrict__ rcv, int* __restrict__ counts) {
    int e = blockIdx.x * 256 + threadIdx.x;
    if (e < NEDGES) atomicAdd(&counts[rcv[e]], 1);
}
__global__ void scan1(const int* __restrict__ counts, int* __restrict__ excl,
                      int* __restrict__ blkSum) {
    __shared__ int tmp[256];
    int tx = threadIdx.x;
    int i = blockIdx.x * 256 + tx;
    int v = (i < NNODES) ? counts[i] : 0;
    tmp[tx] = v;
    __syncthreads();
    for (int off = 1; off < 256; off <<= 1) {
        int t = (tx >= off) ? tmp[tx - off] : 0;
        __syncthreads();
        tmp[tx] += t;
        __syncthreads();
    }
    if (i < NNODES) excl[i] = tmp[tx] - v;
    if (tx == 255) blkSum[blockIdx.x] = tmp[255];
}
__global__ void scan2(const int* __restrict__ blkSum, int* __restrict__ blkOff) {
    __shared__ int tmp[256];
    int tx = threadIdx.x;
    int v = (tx < SCAN_BLOCKS) ? blkSum[tx] : 0;
    tmp[tx] = v;
    __syncthreads();
    for (int off = 1; off < 256; off <<= 1) {
        int t = (tx >= off) ? tmp[tx - off] : 0;
        __syncthreads();
        tmp[tx] += t;
        __syncthreads();
    }
    if (tx < SCAN_BLOCKS) blkOff[tx] = tmp[tx] - v;
}
__global__ void scan3(const int* __restrict__ excl, const int* __restrict__ blkOff,
                      int* __restrict__ cursor) {
    int i = blockIdx.x * 256 + threadIdx.x;
    if (i < NNODES) cursor[i] = excl[i] + blkOff[blockIdx.x];
}
__global__ void scatter_kernel(const int* __restrict__ rcv, int* __restrict__ cursor,
                               int* __restrict__ perm) {
    int e = blockIdx.x * 256 + threadIdx.x;
    if (e < NEDGES) {
        int p = atomicAdd(&cursor[rcv[e]], 1);
        perm[p] = e;
    }
}

struct __align__(16) EdgeLds {
    u16   m1[64 * 136];
    u16   msg[64 * 136];
    int   snd[64];
    int   rcvloc[64];
    float radial[64];
    float diff[64][4];
    float pcpart[4][64];
    float wlast[128];
    float b1[128];
};   // 38656 B -> 4 blocks/CU

// 4 waves; wave w owns cols [32w, 32w+32). Edges processed in receiver-sorted order.
__global__ __launch_bounds__(256, 4) void edge_kernel(
    const u16* __restrict__ P, const float* __restrict__ pos,
    const int* __restrict__ snd, const int* __restrict__ rcv,
    const int* __restrict__ perm,
    const float* __restrict__ eW1last, const float* __restrict__ eb1,
    const u16* __restrict__ eW2T, const float* __restrict__ eb2,
    const u16* __restrict__ pW1T, const float* __restrict__ pb1,
    const float* __restrict__ pW2,
    float* __restrict__ agg, float* __restrict__ posacc)
{
    __shared__ EdgeLds S;
    const int tid  = threadIdx.x;
    const int w    = tid >> 6;
    const int lane = tid & 63;
    const int m    = lane & 15;
    const int quad = lane >> 4;
    const int ksub = quad * 8;

    bf16x8 bw2[4][2], bp1[4][2];
    float b2v[2], pb1v[2], pw2v[2];
    #pragma unroll
    for (int cc = 0; cc < 2; cc++) {
        int col = (2 * w + cc) * 16 + m;
        #pragma unroll
        for (int t = 0; t < 4; t++) {
            bw2[t][cc] = ld8(eW2T + col * 128 + t * 32 + ksub);
            bp1[t][cc] = ld8(pW1T + col * 128 + t * 32 + ksub);
        }
        b2v[cc]  = eb2[col];
        pb1v[cc] = pb1[col];
        pw2v[cc] = pW2[col];
    }
    if (tid < 128) { S.wlast[tid] = eW1last[tid]; S.b1[tid] = eb1[tid]; }

    for (int base = blockIdx.x * 64; base < NEDGES; base += gridDim.x * 64) {
        __syncthreads();
        if (tid < 64) {
            int e = perm[base + tid];
            int s = snd[e], r = rcv[e];
            S.snd[tid] = s; S.rcvloc[tid] = r;
            float rad = 0.f;
            #pragma unroll
            for (int c = 0; c < 3; c++) {
                float d = pos[s * 3 + c] - pos[r * 3 + c];
                S.diff[tid][c] = d;
                rad += d * d;
            }
            S.radial[tid] = rad;
        }
        __syncthreads();
        // ---- layer1 (no MFMA): m1 = silu(Pa[s] + Pb[r] + rad*wlast + b1) ----
        #pragma unroll
        for (int k = 0; k < 8; k++) {
            int cid = tid + k * 256;    // 0..2047
            int e = cid >> 5;           // row
            int p = cid & 31;           // 4-col granule
            int s = S.snd[e], r = S.rcvloc[e];
            float rad = S.radial[e];
            U4 pa, pb, o;
            pa.v = *(const ushort4*)(P + (size_t)s * 384 + p * 4);
            pb.v = *(const ushort4*)(P + (size_t)r * 384 + 128 + p * 4);
            #pragma unroll
            for (int j = 0; j < 4; j++) {
                int col = p * 4 + j;
                float v = bf2f(pa.a[j]) + bf2f(pb.a[j]) + rad * S.wlast[col] + S.b1[col];
                o.a[j] = f2bf(silu(v));
            }
            *(ushort4*)&S.m1[e * 136 + p * 4] = o.v;
        }
        __syncthreads();
        // ---- layer2: msg = silu(m1 @ eW2 + b2) ----
        #pragma unroll
        for (int mt = 0; mt < 4; mt++) {
            f32x4 acc0 = (f32x4){0,0,0,0}, acc1 = (f32x4){0,0,0,0};
            #pragma unroll
            for (int t = 0; t < 4; t++) {
                bf16x8 a = *(const bf16x8*)&S.m1[(mt * 16 + m) * 136 + t * 32 + ksub];
                acc0 = mfma16(a, bw2[t][0], acc0);
                acc1 = mfma16(a, bw2[t][1], acc1);
            }
            #pragma unroll
            for (int cc = 0; cc < 2; cc++) {
                f32x4 acc = cc ? acc1 : acc0;
                int col = (2 * w + cc) * 16 + m;
                #pragma unroll
                for (int r = 0; r < 4; r++) {
                    int row = mt * 16 + quad * 4 + r;
                    S.msg[row * 136 + col] = f2bf(silu(acc[r] + b2v[cc]));
                }
            }
        }
        __syncthreads();
        // ---- pos head ----
        #pragma unroll
        for (int mt = 0; mt < 4; mt++) {
            f32x4 acc0 = (f32x4){0,0,0,0}, acc1 = (f32x4){0,0,0,0};
            #pragma unroll
            for (int t = 0; t < 4; t++) {
                bf16x8 a = *(const bf16x8*)&S.msg[(mt * 16 + m) * 136 + t * 32 + ksub];
                acc0 = mfma16(a, bp1[t][0], acc0);
                acc1 = mfma16(a, bp1[t][1], acc1);
            }
            float p4[4];
            #pragma unroll
            for (int r = 0; r < 4; r++)
                p4[r] = silu(acc0[r] + pb1v[0]) * pw2v[0]
                      + silu(acc1[r] + pb1v[1]) * pw2v[1];
            #pragma unroll
            for (int mask = 1; mask < 16; mask <<= 1) {
                #pragma unroll
                for (int r = 0; r < 4; r++) p4[r] += __shfl_xor(p4[r], mask);
            }
            if (m == 0) {
                #pragma unroll
                for (int r = 0; r < 4; r++)
                    S.pcpart[w][mt * 16 + quad * 4 + r] = p4[r];
            }
        }
        // ---- agg: segment-walk over receiver-sorted rows, flush per boundary ----
        {
            int half = tid >> 7, col = tid & 127;
            int r0 = half * 32;
            float a = 0.f;
            int cur = S.rcvloc[r0];
            for (int r = r0; r < r0 + 32; ++r) {
                int rc = S.rcvloc[r];
                if (rc != cur) {
                    atomicAdd(&agg[(size_t)cur * 128 + col], a);
                    a = 0.f; cur = rc;
                }
                a += bf2f(S.msg[r * 136 + col]);
            }
            atomicAdd(&agg[(size_t)cur * 128 + col], a);
        }
        __syncthreads();
        if (tid < 192) {
            int e = tid / 3, c = tid - e * 3;
            float pc = S.pcpart[0][e] + S.pcpart[1][e] + S.pcpart[2][e] + S.pcpart[3][e];
            float tr = S.diff[e][c] * pc;
            tr = fminf(fmaxf(tr, -100.f), 100.f);
            atomicAdd(&posacc[S.snd[e] * 3 + c], tr);
        }
    }
}

// Node MLP: layer1 agg-part MFMA + precomputed Pn; layer2 + residual.
__global__ __launch_bounds__(256, 4) void node_kernel(
    const u16* __restrict__ P, const float* __restrict__ h,
    const float* __restrict__ agg,
    const u16* __restrict__ nW1T, const float* __restrict__ nb1,
    const u16* __restrict__ nW2T, const float* __restrict__ nb2,
    float* __restrict__ out)
{
    __shared__ alignas(16) u16 m1[64 * 136];
    const int tid  = threadIdx.x;
    const int w    = tid >> 6;
    const int lane = tid & 63;
    const int m    = lane & 15;
    const int quad = lane >> 4;
    const int ksub = quad * 8;

    bf16x8 bw1[4][2], bw2[4][2];
    float b1v[2], b2v[2];
    #pragma unroll
    for (int cc = 0; cc < 2; cc++) {
        int col = (2 * w + cc) * 16 + m;
        #pragma unroll
        for (int t = 0; t < 4; t++) {
            bw1[t][cc] = ld8(nW1T + col * 256 + 128 + t * 32 + ksub);  // agg rows
            bw2[t][cc] = ld8(nW2T + col * 128 + t * 32 + ksub);
        }
        b1v[cc] = nb1[col];
        b2v[cc] = nb2[col];
    }
    const int base = blockIdx.x * 64;
    #pragma unroll
    for (int mt = 0; mt < 4; mt++) {
        int nm = base + mt * 16 + m;
        if (nm >= NNODES) nm = NNODES - 1;
        f32x4 acc0 = (f32x4){0,0,0,0}, acc1 = (f32x4){0,0,0,0};
        #pragma unroll
        for (int t = 0; t < 4; t++) {
            const float* ap = agg + (size_t)nm * 128 + t * 32 + ksub;
            f32x4 lo = *(const f32x4*)ap;
            f32x4 hi = *(const f32x4*)(ap + 4);
            bf16x8 a;
            #pragma unroll
            for (int j = 0; j < 4; j++) {
                a[j]     = (short)f2bf(lo[j]);
                a[4 + j] = (short)f2bf(hi[j]);
            }
            acc0 = mfma16(a, bw1[t][0], acc0);
            acc1 = mfma16(a, bw1[t][1], acc1);
        }
        #pragma unroll
        for (int cc = 0; cc < 2; cc++) {
            f32x4 acc = cc ? acc1 : acc0;
            int col = (2 * w + cc) * 16 + m;
            #pragma unroll
            for (int r = 0; r < 4; r++) {
                int row = mt * 16 + quad * 4 + r;
                int nrc = base + row; if (nrc >= NNODES) nrc = NNODES - 1;
                float v = acc[r] + bf2f(P[(size_t)nrc * 384 + 256 + col]) + b1v[cc];
                m1[row * 136 + col] = f2bf(silu(v));
            }
        }
    }
    __syncthreads();
    #pragma unroll
    for (int mt = 0; mt < 4; mt++) {
        f32x4 acc0 = (f32x4){0,0,0,0}, acc1 = (f32x4){0,0,0,0};
        #pragma unroll
        for (int t = 0; t < 4; t++) {
            bf16x8 a = *(const bf16x8*)&m1[(mt * 16 + m) * 136 + t * 32 + ksub];
            acc0 = mfma16(a, bw2[t][0], acc0);
            acc1 = mfma16(a, bw2[t][1], acc1);
        }
        #pragma unroll
        for (int cc = 0; cc < 2; cc++) {
            f32x4 acc = cc ? acc1 : acc0;
            int col = (2 * w + cc) * 16 + m;
            #pragma unroll
            for (int r = 0; r < 4; r++) {
                int nr = base + mt * 16 + quad * 4 + r;
                if (nr < NNODES)
                    out[(size_t)nr * 128 + col] = acc[r] + b2v[cc] + h[(size_t)nr * 128 + col];
            }
        }
    }
}

__global__ void pos_kernel(const float* __restrict__ pos,
                           const float* __restrict__ posacc,
                           float* __restrict__ out) {
    int i = blockIdx.x * 256 + threadIdx.x;
    if (i < NNODES * 3) {
        out[NNODES * 128 + i] = pos[i] + posacc[i];
    }
}

extern "C" void kernel_launch(void* const* d_in, const int* in_sizes, int n_in,
                              void* d_out, int out_size, void* d_ws, size_t ws_size,
                              hipStream_t stream) {
    (void)in_sizes; (void)n_in; (void)out_size; (void)ws_size;
    const float* h   = (const float*)d_in[0];
    const float* pos = (const float*)d_in[1];
    const int*   snd = (const int*)d_in[2];
    const int*   rcv = (const int*)d_in[3];
    const float* eW1 = (const float*)d_in[4];
    const float* eb1 = (const float*)d_in[5];
    const float* eW2 = (const float*)d_in[6];
    const float* eb2 = (const float*)d_in[7];
    const float* nW1 = (const float*)d_in[8];
    const float* nb1 = (const float*)d_in[9];
    const float* nW2 = (const float*)d_in[10];
    const float* nb2 = (const float*)d_in[11];
    const float* pW1 = (const float*)d_in[12];
    const float* pb1 = (const float*)d_in[13];
    const float* pW2 = (const float*)d_in[14];
    float* out = (float*)d_out;

    float* agg    = (float*)d_ws;                       // [N,128] f32
    float* posacc = agg + (size_t)NNODES * 128;         // [N,3]
    u16* P    = (u16*)(posacc + (size_t)NNODES * 3);    // [N,384] bf16
    u16* eW1T = P + (size_t)NNODES * 384;               // [128][256]
    u16* eW2T = eW1T + 128 * 256;                       // [128][128]
    u16* pW1T = eW2T + 128 * 128;
    u16* nW1T = pW1T + 128 * 128;                       // [128][256]
    u16* nW2T = nW1T + 128 * 256;
    int* counts = (int*)(nW2T + 128 * 128);             // [50048]
    int* excl   = counts + 50048;
    int* blkSum = excl + 50048;                         // [256]
    int* blkOff = blkSum + 256;                         // [256]
    int* cursor = blkOff + 256;                         // [50048]
    int* perm   = cursor + 50048;                       // [E]

    hipMemsetAsync(agg, 0, (size_t)NNODES * 131 * sizeof(float), stream);
    hipMemsetAsync(counts, 0, 50048 * sizeof(int), stream);

    transpose_cvt<<<(256 * 128 + 255) / 256, 256, 0, stream>>>(eW1, eW1T, 256, 128);
    transpose_cvt<<<(128 * 128 + 255) / 256, 256, 0, stream>>>(eW2, eW2T, 128, 128);
    transpose_cvt<<<(128 * 128 + 255) / 256, 256, 0, stream>>>(pW1, pW1T, 128, 128);
    transpose_cvt<<<(256 * 128 + 255) / 256, 256, 0, stream>>>(nW1, nW1T, 256, 128);
    transpose_cvt<<<(128 * 128 + 255) / 256, 256, 0, stream>>>(nW2, nW2T, 128, 128);

    gemm_p<<<(NNODES + 63) / 64, 256, 0, stream>>>(h, eW1T, nW1T, P);

    hist_kernel<<<(NEDGES + 255) / 256, 256, 0, stream>>>(rcv, counts);
    scan1<<<SCAN_BLOCKS, 256, 0, stream>>>(counts, excl, blkSum);
    scan2<<<1, 256, 0, stream>>>(blkSum, blkOff);
    scan3<<<SCAN_BLOCKS, 256, 0, stream>>>(excl, blkOff, cursor);
    scatter_kernel<<<(NEDGES + 255) / 256, 256, 0, stream>>>(rcv, cursor, perm);

    edge_kernel<<<EB, 256, 0, stream>>>(
        P, pos, snd, rcv, perm,
        eW1 + 256 * 128, eb1,
        eW2T, eb2, pW1T, pb1, pW2,
        agg, posacc);

    node_kernel<<<(NNODES + 63) / 64, 256, 0, stream>>>(
        P, h, agg, nW1T, nb1, nW2T, nb2, out);

    pos_kernel<<<(NNODES * 3 + 255) / 256, 256, 0, stream>>>(pos, posacc, out);
}

// Round 5
// 449.767 us; speedup vs baseline: 2.1685x; 1.1472x over previous
//
#include <hip/hip_runtime.h>
#include <hip/hip_bf16.h>

#define NNODES 50000
#define NEDGES 800000
#define EB 1024          // edge grid: 4 blocks/CU resident
#define SCAN_BLOCKS 196  // ceil(50000/256)
#define TRN_BLOCKS 448   // 114688 weight elems / 256

typedef short bf16x8 __attribute__((ext_vector_type(8)));
typedef float f32x4 __attribute__((ext_vector_type(4)));
typedef unsigned short u16;
typedef unsigned int u32;

__device__ __forceinline__ u16 f2bf(float f) {
    __hip_bfloat16 b = __float2bfloat16(f);
    return *reinterpret_cast<u16*>(&b);
}
__device__ __forceinline__ float bf2f(u16 v) {
    u32 u = ((u32)v) << 16;
    return __uint_as_float(u);
}
__device__ __forceinline__ u32 pack2(float a, float b) {
    __hip_bfloat162 t = __float22bfloat162_rn(float2{a, b});
    return *reinterpret_cast<u32*>(&t);
}
// silu without IEEE divide: x * rcp(1 + 2^(-x*log2e))
__device__ __forceinline__ float fast_silu(float x) {
    float e = __builtin_amdgcn_exp2f(-1.442695040888963f * x);
    return x * __builtin_amdgcn_rcpf(1.0f + e);
}
__device__ __forceinline__ bf16x8 ld8(const u16* p) {
    return *(const bf16x8*)p;
}
__device__ __forceinline__ f32x4 mfma16(bf16x8 a, bf16x8 b, f32x4 c) {
    return __builtin_amdgcn_mfma_f32_16x16x32_bf16(a, b, c, 0, 0, 0);
}

// ---- prep: 5 weight transposes (fp32->bf16) + receiver histogram ----
__global__ void prep_kernel(const float* __restrict__ eW1, const float* __restrict__ eW2,
                            const float* __restrict__ pW1, const float* __restrict__ nW1,
                            const float* __restrict__ nW2,
                            u16* __restrict__ eW1T, u16* __restrict__ eW2T,
                            u16* __restrict__ pW1T, u16* __restrict__ nW1T,
                            u16* __restrict__ nW2T,
                            const int* __restrict__ rcv, int* __restrict__ counts) {
    int b = blockIdx.x;
    if (b < TRN_BLOCKS) {
        int i = b * 256 + threadIdx.x;
        const float* src; u16* dst; int K;
        if (i < 32768)      { src = eW1; dst = eW1T; K = 256; }
        else if (i < 49152) { src = eW2; dst = eW2T; K = 128; i -= 32768; }
        else if (i < 65536) { src = pW1; dst = pW1T; K = 128; i -= 49152; }
        else if (i < 98304) { src = nW1; dst = nW1T; K = 256; i -= 65536; }
        else                { src = nW2; dst = nW2T; K = 128; i -= 98304; }
        int n = i / K, k = i - n * K;
        dst[i] = f2bf(src[k * 128 + n]);
    } else {
        int e = (b - TRN_BLOCKS) * 256 + threadIdx.x;
        if (e < NEDGES) atomicAdd(&counts[rcv[e]], 1);
    }
}

// ---- P precompute: P[n] = [h@eW1a + eb1/2 | h@eW1b + eb1/2 | h@nW1a] (bf16) ----
__global__ __launch_bounds__(256) void gemm_p(
    const float* __restrict__ h, const u16* __restrict__ eW1T,
    const u16* __restrict__ nW1T, const float* __restrict__ eb1,
    u16* __restrict__ P)
{
    const int tid  = threadIdx.x;
    const int w    = tid >> 6;
    const int lane = tid & 63;
    const int m    = lane & 15;
    const int quad = lane >> 4;
    const int ksub = quad * 8;

    bf16x8 bw[4][6];
    float bias[6];
    #pragma unroll
    for (int cc = 0; cc < 6; cc++) {
        int C = 96 * w + 16 * cc + m;
        const u16* bp;
        if (C < 128)      { bp = eW1T + C * 256;               bias[cc] = 0.5f * eb1[C]; }
        else if (C < 256) { bp = eW1T + (C - 128) * 256 + 128; bias[cc] = 0.5f * eb1[C - 128]; }
        else              { bp = nW1T + (C - 256) * 256;       bias[cc] = 0.f; }
        #pragma unroll
        for (int t = 0; t < 4; t++) bw[t][cc] = ld8(bp + t * 32 + ksub);
    }
    const int base = blockIdx.x * 64;
    #pragma unroll
    for (int mt = 0; mt < 4; mt++) {
        int nm = base + mt * 16 + m;
        if (nm >= NNODES) nm = NNODES - 1;
        bf16x8 afr[4];
        #pragma unroll
        for (int t = 0; t < 4; t++) {
            const float* ap = h + (size_t)nm * 128 + t * 32 + ksub;
            f32x4 lo = *(const f32x4*)ap;
            f32x4 hi = *(const f32x4*)(ap + 4);
            #pragma unroll
            for (int j = 0; j < 4; j++) {
                afr[t][j]     = (short)f2bf(lo[j]);
                afr[t][4 + j] = (short)f2bf(hi[j]);
            }
        }
        f32x4 acc[6];
        #pragma unroll
        for (int cc = 0; cc < 6; cc++) acc[cc] = (f32x4){0,0,0,0};
        #pragma unroll
        for (int t = 0; t < 4; t++)
            #pragma unroll
            for (int cc = 0; cc < 6; cc++)
                acc[cc] = mfma16(afr[t], bw[t][cc], acc[cc]);
        #pragma unroll
        for (int cc = 0; cc < 6; cc++) {
            int C = 96 * w + 16 * cc + m;
            #pragma unroll
            for (int r = 0; r < 4; r++) {
                int nr = base + mt * 16 + quad * 4 + r;
                if (nr < NNODES) P[(size_t)nr * 384 + C] = f2bf(acc[cc][r] + bias[cc]);
            }
        }
    }
}

// ---- scan chain ----
__global__ void scan1(const int* __restrict__ counts, int* __restrict__ excl,
                      int* __restrict__ blkSum) {
    __shared__ int tmp[256];
    int tx = threadIdx.x;
    int i = blockIdx.x * 256 + tx;
    int v = (i < NNODES) ? counts[i] : 0;
    tmp[tx] = v;
    __syncthreads();
    for (int off = 1; off < 256; off <<= 1) {
        int t = (tx >= off) ? tmp[tx - off] : 0;
        __syncthreads();
        tmp[tx] += t;
        __syncthreads();
    }
    if (i < NNODES) excl[i] = tmp[tx] - v;
    if (tx == 255) blkSum[blockIdx.x] = tmp[255];
}
__global__ void scan2(const int* __restrict__ blkSum, int* __restrict__ blkOff) {
    __shared__ int tmp[256];
    int tx = threadIdx.x;
    int v = (tx < SCAN_BLOCKS) ? blkSum[tx] : 0;
    tmp[tx] = v;
    __syncthreads();
    for (int off = 1; off < 256; off <<= 1) {
        int t = (tx >= off) ? tmp[tx - off] : 0;
        __syncthreads();
        tmp[tx] += t;
        __syncthreads();
    }
    if (tx < SCAN_BLOCKS) blkOff[tx] = tmp[tx] - v;
}
__global__ void scan3(const int* __restrict__ excl, const int* __restrict__ blkOff,
                      int* __restrict__ cursor) {
    int i = blockIdx.x * 256 + threadIdx.x;
    if (i < NNODES) cursor[i] = excl[i] + blkOff[blockIdx.x];
}
__global__ void scatter_kernel(const int* __restrict__ rcv, int* __restrict__ cursor,
                               int* __restrict__ perm) {
    int e = blockIdx.x * 256 + threadIdx.x;
    if (e < NEDGES) {
        int p = atomicAdd(&cursor[rcv[e]], 1);
        perm[p] = e;
    }
}

struct __align__(16) EdgeLds {
    u16   m1[64 * 136];       // XOR-swizzled 8-col chunks
    u16   msg[64 * 136];
    float diff[64][4];
    float pcpart[4][64];
    float wlast[128];
    float radial[64];
    int   sndloc[64];
    int   rcvloc[64];
};   // ~38 KB -> 4 blocks/CU

__global__ __launch_bounds__(256, 4) void edge_kernel(
    const u16* __restrict__ P, const float* __restrict__ pos,
    const int* __restrict__ snd, const int* __restrict__ rcv,
    const int* __restrict__ perm,
    const float* __restrict__ eW1last,
    const u16* __restrict__ eW2T, const float* __restrict__ eb2,
    const u16* __restrict__ pW1T, const float* __restrict__ pb1,
    const float* __restrict__ pW2,
    float* __restrict__ agg, float* __restrict__ posacc)
{
    __shared__ EdgeLds S;
    const int tid  = threadIdx.x;
    const int w    = tid >> 6;
    const int lane = tid & 63;
    const int m    = lane & 15;
    const int quad = lane >> 4;
    const int ksub = quad * 8;

    bf16x8 bw2[4][2], bp1[4][2];
    float b2v[2], pb1v[2], pw2v[2];
    #pragma unroll
    for (int cc = 0; cc < 2; cc++) {
        int col = (2 * w + cc) * 16 + m;
        #pragma unroll
        for (int t = 0; t < 4; t++) {
            bw2[t][cc] = ld8(eW2T + col * 128 + t * 32 + ksub);
            bp1[t][cc] = ld8(pW1T + col * 128 + t * 32 + ksub);
        }
        b2v[cc]  = eb2[col];
        pb1v[cc] = pb1[col];
        pw2v[cc] = pW2[col];
    }
    if (tid < 128) S.wlast[tid] = eW1last[tid];

    for (int base = blockIdx.x * 64; base < NEDGES; base += gridDim.x * 64) {
        __syncthreads();
        // every thread resolves its row's edge (4x redundant, L1-cached)
        const int e = lane;
        int eg = perm[base + e];
        int s = snd[eg], r = rcv[eg];
        if (tid < 64) {
            S.sndloc[tid] = s; S.rcvloc[tid] = r;
            float rad = 0.f;
            #pragma unroll
            for (int c = 0; c < 3; c++) {
                float d = pos[s * 3 + c] - pos[r * 3 + c];
                S.diff[tid][c] = d;
                rad += d * d;
            }
            S.radial[tid] = rad;
        }
        __syncthreads();
        // ---- layer1: m1 = silu(Pa[s] + Pb[r] + rad*wlast)  (bias pre-folded) ----
        {
            float rad = S.radial[e];
            const u16* pa = P + (size_t)s * 384 + w * 32;
            const u16* pb = P + (size_t)r * 384 + 128 + w * 32;
            const int sw = e >> 3;
            #pragma unroll
            for (int k = 0; k < 4; k++) {
                bf16x8 va = ld8(pa + k * 8);
                bf16x8 vb = ld8(pb + k * 8);
                u32 pk[4];
                #pragma unroll
                for (int jj = 0; jj < 4; jj++) {
                    int col = w * 32 + k * 8 + jj * 2;
                    float2 wl = *(const float2*)&S.wlast[col];
                    float v0 = bf2f((u16)va[jj * 2])     + bf2f((u16)vb[jj * 2])     + rad * wl.x;
                    float v1 = bf2f((u16)va[jj * 2 + 1]) + bf2f((u16)vb[jj * 2 + 1]) + rad * wl.y;
                    pk[jj] = pack2(fast_silu(v0), fast_silu(v1));
                }
                int chunk = (w * 4 + k) ^ sw;
                *(uint4*)&S.m1[e * 136 + chunk * 8] =
                    make_uint4(pk[0], pk[1], pk[2], pk[3]);
            }
        }
        __syncthreads();
        // ---- layer2: msg = silu(m1 @ eW2 + b2) ----
        #pragma unroll
        for (int mt = 0; mt < 4; mt++) {
            const int rs = mt * 2 + (m >> 3);
            const int row = mt * 16 + m;
            f32x4 acc0 = (f32x4){0,0,0,0}, acc1 = (f32x4){0,0,0,0};
            #pragma unroll
            for (int t = 0; t < 4; t++) {
                bf16x8 a = *(const bf16x8*)&S.m1[row * 136 + ((t * 4 + quad) ^ rs) * 8];
                acc0 = mfma16(a, bw2[t][0], acc0);
                acc1 = mfma16(a, bw2[t][1], acc1);
            }
            #pragma unroll
            for (int cc = 0; cc < 2; cc++) {
                f32x4 acc = cc ? acc1 : acc0;
                int col = (2 * w + cc) * 16 + m;
                #pragma unroll
                for (int rr = 0; rr < 4; rr++) {
                    int orow = mt * 16 + quad * 4 + rr;
                    S.msg[orow * 136 + col] = f2bf(fast_silu(acc[rr] + b2v[cc]));
                }
            }
        }
        __syncthreads();
        // ---- pos head: pc = silu(msg @ pW1 + pb1) @ pW2 (per-wave partials) ----
        #pragma unroll
        for (int mt = 0; mt < 4; mt++) {
            f32x4 acc0 = (f32x4){0,0,0,0}, acc1 = (f32x4){0,0,0,0};
            #pragma unroll
            for (int t = 0; t < 4; t++) {
                bf16x8 a = *(const bf16x8*)&S.msg[(mt * 16 + m) * 136 + t * 32 + ksub];
                acc0 = mfma16(a, bp1[t][0], acc0);
                acc1 = mfma16(a, bp1[t][1], acc1);
            }
            float p4[4];
            #pragma unroll
            for (int rr = 0; rr < 4; rr++)
                p4[rr] = fast_silu(acc0[rr] + pb1v[0]) * pw2v[0]
                       + fast_silu(acc1[rr] + pb1v[1]) * pw2v[1];
            #pragma unroll
            for (int mask = 1; mask < 16; mask <<= 1) {
                #pragma unroll
                for (int rr = 0; rr < 4; rr++) p4[rr] += __shfl_xor(p4[rr], mask);
            }
            if (m == 0) {
                #pragma unroll
                for (int rr = 0; rr < 4; rr++)
                    S.pcpart[w][mt * 16 + quad * 4 + rr] = p4[rr];
            }
        }
        // ---- agg: segment walk over receiver-sorted rows ----
        {
            int half = tid >> 7, col = tid & 127;
            int r0 = half * 32;
            float a = 0.f;
            int cur = S.rcvloc[r0];
            for (int rr = r0; rr < r0 + 32; ++rr) {
                int rc = S.rcvloc[rr];
                if (rc != cur) {
                    atomicAdd(&agg[(size_t)cur * 128 + col], a);
                    a = 0.f; cur = rc;
                }
                a += bf2f(S.msg[rr * 136 + col]);
            }
            atomicAdd(&agg[(size_t)cur * 128 + col], a);
        }
        __syncthreads();
        if (tid < 192) {
            int ee = tid / 3, c = tid - ee * 3;
            float pc = S.pcpart[0][ee] + S.pcpart[1][ee] + S.pcpart[2][ee] + S.pcpart[3][ee];
            float tr = S.diff[ee][c] * pc;
            tr = fminf(fmaxf(tr, -100.f), 100.f);
            atomicAdd(&posacc[S.sndloc[ee] * 3 + c], tr);
        }
    }
}

// Node MLP (+ fused pos output): h_new = h + (silu([h,agg]@nW1+nb1)@nW2+nb2)
__global__ __launch_bounds__(256, 4) void node_kernel(
    const u16* __restrict__ P, const float* __restrict__ h,
    const float* __restrict__ agg,
    const u16* __restrict__ nW1T, const float* __restrict__ nb1,
    const u16* __restrict__ nW2T, const float* __restrict__ nb2,
    const float* __restrict__ pos, const float* __restrict__ posacc,
    float* __restrict__ out)
{
    __shared__ alignas(16) u16 m1[64 * 136];
    const int tid  = threadIdx.x;
    const int w    = tid >> 6;
    const int lane = tid & 63;
    const int m    = lane & 15;
    const int quad = lane >> 4;
    const int ksub = quad * 8;

    bf16x8 bw1[4][2], bw2[4][2];
    float b1v[2], b2v[2];
    #pragma unroll
    for (int cc = 0; cc < 2; cc++) {
        int col = (2 * w + cc) * 16 + m;
        #pragma unroll
        for (int t = 0; t < 4; t++) {
            bw1[t][cc] = ld8(nW1T + col * 256 + 128 + t * 32 + ksub);  // agg rows of nW1
            bw2[t][cc] = ld8(nW2T + col * 128 + t * 32 + ksub);
        }
        b1v[cc] = nb1[col];
        b2v[cc] = nb2[col];
    }
    const int base = blockIdx.x * 64;
    #pragma unroll
    for (int mt = 0; mt < 4; mt++) {
        int nm = base + mt * 16 + m;
        if (nm >= NNODES) nm = NNODES - 1;
        f32x4 acc0 = (f32x4){0,0,0,0}, acc1 = (f32x4){0,0,0,0};
        #pragma unroll
        for (int t = 0; t < 4; t++) {
            const float* ap = agg + (size_t)nm * 128 + t * 32 + ksub;
            f32x4 lo = *(const f32x4*)ap;
            f32x4 hi = *(const f32x4*)(ap + 4);
            bf16x8 a;
            #pragma unroll
            for (int j = 0; j < 4; j++) {
                a[j]     = (short)f2bf(lo[j]);
                a[4 + j] = (short)f2bf(hi[j]);
            }
            acc0 = mfma16(a, bw1[t][0], acc0);
            acc1 = mfma16(a, bw1[t][1], acc1);
        }
        #pragma unroll
        for (int cc = 0; cc < 2; cc++) {
            f32x4 acc = cc ? acc1 : acc0;
            int col = (2 * w + cc) * 16 + m;
            #pragma unroll
            for (int rr = 0; rr < 4; rr++) {
                int row = mt * 16 + quad * 4 + rr;
                int nrc = base + row; if (nrc >= NNODES) nrc = NNODES - 1;
                float v = acc[rr] + bf2f(P[(size_t)nrc * 384 + 256 + col]) + b1v[cc];
                m1[row * 136 + col] = f2bf(fast_silu(v));
            }
        }
    }
    __syncthreads();
    #pragma unroll
    for (int mt = 0; mt < 4; mt++) {
        f32x4 acc0 = (f32x4){0,0,0,0}, acc1 = (f32x4){0,0,0,0};
        #pragma unroll
        for (int t = 0; t < 4; t++) {
            bf16x8 a = *(const bf16x8*)&m1[(mt * 16 + m) * 136 + t * 32 + ksub];
            acc0 = mfma16(a, bw2[t][0], acc0);
            acc1 = mfma16(a, bw2[t][1], acc1);
        }
        #pragma unroll
        for (int cc = 0; cc < 2; cc++) {
            f32x4 acc = cc ? acc1 : acc0;
            int col = (2 * w + cc) * 16 + m;
            #pragma unroll
            for (int rr = 0; rr < 4; rr++) {
                int nr = base + mt * 16 + quad * 4 + rr;
                if (nr < NNODES)
                    out[(size_t)nr * 128 + col] = acc[rr] + b2v[cc] + h[(size_t)nr * 128 + col];
            }
        }
    }
    // fused pos output: 192 elems per block covers 150144 >= 150000
    if (tid < 192) {
        int i = blockIdx.x * 192 + tid;
        if (i < NNODES * 3) out[NNODES * 128 + i] = pos[i] + posacc[i];
    }
}

extern "C" void kernel_launch(void* const* d_in, const int* in_sizes, int n_in,
                              void* d_out, int out_size, void* d_ws, size_t ws_size,
                              hipStream_t stream) {
    (void)in_sizes; (void)n_in; (void)out_size; (void)ws_size;
    const float* h   = (const float*)d_in[0];
    const float* pos = (const float*)d_in[1];
    const int*   snd = (const int*)d_in[2];
    const int*   rcv = (const int*)d_in[3];
    const float* eW1 = (const float*)d_in[4];
    const float* eb1 = (const float*)d_in[5];
    const float* eW2 = (const float*)d_in[6];
    const float* eb2 = (const float*)d_in[7];
    const float* nW1 = (const float*)d_in[8];
    const float* nb1 = (const float*)d_in[9];
    const float* nW2 = (const float*)d_in[10];
    const float* nb2 = (const float*)d_in[11];
    const float* pW1 = (const float*)d_in[12];
    const float* pb1 = (const float*)d_in[13];
    const float* pW2 = (const float*)d_in[14];
    float* out = (float*)d_out;

    float* agg    = (float*)d_ws;                       // [N,128] f32
    float* posacc = agg + (size_t)NNODES * 128;         // [N,3]
    u16* P    = (u16*)(posacc + (size_t)NNODES * 3);    // [N,384] bf16
    u16* eW1T = P + (size_t)NNODES * 384;               // [128][256]
    u16* eW2T = eW1T + 128 * 256;                       // [128][128]
    u16* pW1T = eW2T + 128 * 128;
    u16* nW1T = pW1T + 128 * 128;                       // [128][256]
    u16* nW2T = nW1T + 128 * 256;
    int* counts = (int*)(nW2T + 128 * 128);             // [50048]
    int* excl   = counts + 50048;
    int* blkSum = excl + 50048;                         // [256]
    int* blkOff = blkSum + 256;                         // [256]
    int* cursor = blkOff + 256;                         // [50048]
    int* perm   = cursor + 50048;                       // [E]

    hipMemsetAsync(agg, 0, (size_t)NNODES * 131 * sizeof(float), stream);
    hipMemsetAsync(counts, 0, 50048 * sizeof(int), stream);

    prep_kernel<<<TRN_BLOCKS + (NEDGES + 255) / 256, 256, 0, stream>>>(
        eW1, eW2, pW1, nW1, nW2, eW1T, eW2T, pW1T, nW1T, nW2T, rcv, counts);

    gemm_p<<<(NNODES + 63) / 64, 256, 0, stream>>>(h, eW1T, nW1T, eb1, P);

    scan1<<<SCAN_BLOCKS, 256, 0, stream>>>(counts, excl, blkSum);
    scan2<<<1, 256, 0, stream>>>(blkSum, blkOff);
    scan3<<<SCAN_BLOCKS, 256, 0, stream>>>(excl, blkOff, cursor);
    scatter_kernel<<<(NEDGES + 255) / 256, 256, 0, stream>>>(rcv, cursor, perm);

    edge_kernel<<<EB, 256, 0, stream>>>(
        P, pos, snd, rcv, perm,
        eW1 + 256 * 128,
        eW2T, eb2, pW1T, pb1, pW2,
        agg, posacc);

    node_kernel<<<(NNODES + 63) / 64, 256, 0, stream>>>(
        P, h, agg, nW1T, nb1, nW2T, nb2, pos, posacc, out);
}